// Round 19
// baseline (728.346 us; speedup 1.0000x reference)
//
#include <hip/hip_runtime.h>
#include <cmath>

typedef __bf16 bhalf;
typedef __bf16 bf16x4 __attribute__((ext_vector_type(4)));
typedef __bf16 bf16x8 __attribute__((ext_vector_type(8)));
typedef float f32x4 __attribute__((ext_vector_type(4)));

#define MFMA16(a, b, c) __builtin_amdgcn_mfma_f32_16x16x32_bf16(a, b, c, 0, 0, 0)

namespace {
constexpr int Bn = 2, Sn = 2048, Cn = 1024, Hn = 16, Dn = 64;
constexpr int Zn = Bn * Hn;     // 32
constexpr int Mn = Bn * Sn;     // 4096
}

__device__ __forceinline__ void cvt_hilo8(const float4& v0, const float4& v1,
                                          bf16x8& hi, bf16x8& lo) {
  float f[8] = {v0.x, v0.y, v0.z, v0.w, v1.x, v1.y, v1.z, v1.w};
#pragma unroll
  for (int i = 0; i < 8; ++i) {
    bhalf h = (bhalf)f[i];
    hi[i] = h;
    lo[i] = (bhalf)(f[i] - (float)h);
  }
}

// Y = A[M,C] @ W[C,C]^T via split-bf16 MFMA (R12 original, best).
template <int MODE, bool A_BF16>
__global__ __launch_bounds__(256) void proj_mfma(
    const void* __restrict__ Av, const void* __restrict__ AvLo,
    const float* __restrict__ W, float* __restrict__ out_f32,
    bhalf* __restrict__ dst_hi, bhalf* __restrict__ dst_lo) {
  __shared__ bhalf BsH[64][40];
  __shared__ bhalf BsL[64][40];
  const int tid = threadIdx.x;
  const int lane = tid & 63, w = tid >> 6;
  const int l15 = lane & 15, lg = lane >> 4;
  const int nB = blockIdx.x << 6, mB = blockIdx.y << 6;
  const int row = mB + w * 16 + l15;
  f32x4 acc[4] = {};

  const int sr = tid >> 2, sc = (tid & 3) << 3;
  for (int k0 = 0; k0 < Cn; k0 += 32) {
    {
      const float* wp = W + (size_t)(nB + sr) * Cn + k0 + sc;
      float4 w0 = *(const float4*)wp;
      float4 w1 = *(const float4*)(wp + 4);
      bf16x8 h, l;
      cvt_hilo8(w0, w1, h, l);
      *(bf16x8*)&BsH[sr][sc] = h;
      *(bf16x8*)&BsL[sr][sc] = l;
    }
    __syncthreads();
    bf16x8 aH, aL;
    if constexpr (A_BF16) {
      aH = *(const bf16x8*)((const bhalf*)Av + (size_t)row * Cn + k0 + lg * 8);
      aL = *(const bf16x8*)((const bhalf*)AvLo + (size_t)row * Cn + k0 + lg * 8);
    } else {
      const float* A = (const float*)Av;
      float4 a0 = *(const float4*)(A + (size_t)row * Cn + k0 + lg * 8);
      float4 a1 = *(const float4*)(A + (size_t)row * Cn + k0 + lg * 8 + 4);
      cvt_hilo8(a0, a1, aH, aL);
    }
#pragma unroll
    for (int j = 0; j < 4; ++j) {
      bf16x8 bH = *(const bf16x8*)&BsH[16 * j + l15][lg * 8];
      bf16x8 bL = *(const bf16x8*)&BsL[16 * j + l15][lg * 8];
      acc[j] = MFMA16(aH, bH, acc[j]);
      acc[j] = MFMA16(aH, bL, acc[j]);
      acc[j] = MFMA16(aL, bH, acc[j]);
    }
    __syncthreads();
  }

  const int mRow = mB + w * 16 + lg * 4;
  if constexpr (MODE == 0) {
#pragma unroll
    for (int j = 0; j < 4; ++j) {
      const int n = nB + 16 * j + l15;
#pragma unroll
      for (int r = 0; r < 4; ++r)
        out_f32[(size_t)(mRow + r) * Cn + n] = acc[j][r];
    }
  } else if constexpr (MODE == 1) {
    const int hh = nB >> 6;
#pragma unroll
    for (int jj = 0; jj < 2; ++jj) {
      const int d1 = 16 * jj + l15;
      const float invf = 1.0f / powf(10000.0f, (float)d1 * (1.0f / 32.0f));
#pragma unroll
      for (int r = 0; r < 4; ++r) {
        const int m = mRow + r;
        const int b = m >> 11, s = m & (Sn - 1);
        float sn, cs;
        sincosf((float)s * invf, &sn, &cs);
        const float y1 = acc[jj][r], y2 = acc[jj + 2][r];
        const float o1 = y1 * cs - y2 * sn;
        const float o2 = y2 * cs + y1 * sn;
        const size_t base = (((size_t)(b * Hn + hh)) * Sn + s) * Dn;
        bhalf h1 = (bhalf)o1, h2 = (bhalf)o2;
        dst_hi[base + d1] = h1;
        dst_lo[base + d1] = (bhalf)(o1 - (float)h1);
        dst_hi[base + d1 + 32] = h2;
        dst_lo[base + d1 + 32] = (bhalf)(o2 - (float)h2);
      }
    }
  } else {
    const int hh = nB >> 6;
#pragma unroll
    for (int j = 0; j < 4; ++j) {
      const int d = 16 * j + l15;
#pragma unroll
      for (int r = 0; r < 4; ++r) {
        const int m = mRow + r;
        const int b = m >> 11, s = m & (Sn - 1);
        dst_hi[(((size_t)(b * Hn + hh)) * Dn + d) * Sn + s] = (bhalf)acc[j][r];
      }
    }
  }
}

__device__ __forceinline__ void load_q(const bhalf* __restrict__ qhH,
                                       const bhalf* __restrict__ qhL,
                                       size_t zrow, int sBt, int l15, int lg,
                                       bf16x8 (&qH)[2][2], bf16x8 (&qL)[2][2]) {
#pragma unroll
  for (int qf = 0; qf < 2; ++qf)
#pragma unroll
    for (int sl = 0; sl < 2; ++sl) {
      const size_t off = (zrow + sBt + qf * 16 + l15) * Dn + sl * 32 + lg * 8;
      qH[qf][sl] = *(const bf16x8*)(qhH + off);
      qL[qf][sl] = *(const bf16x8*)(qhL + off);
    }
}

// Fused attention v12: producer/consumer wave specialization.
// 512 thr = 4 compute waves (R12-v9 pipeline, no global stores) + 4 store
// waves (drain double-buffered pt -> NT stores, nothing else). One
// __syncthreads per 32-key chunk hands buf[cc&1] to the store waves.
__global__ __launch_bounds__(512, 4) void attn_fused(
    const bhalf* __restrict__ qhH, const bhalf* __restrict__ qhL,
    const bhalf* __restrict__ khH, const bhalf* __restrict__ khL,
    const bhalf* __restrict__ vt, float* __restrict__ attn,
    bhalf* __restrict__ ctxH, bhalf* __restrict__ ctxL) {
  __shared__ float ptd[2][4][32][36];   // double-buffered p staging
  __shared__ float obuf[4][16][72];     // epilogue ctx partials
  __shared__ float lsum[4][32];
  __shared__ float linv[32];

  const int tid = threadIdx.x, lane = tid & 63, w = tid >> 6;
  const int l15 = lane & 15, lg = lane >> 4;
  const bool isC = (w < 4);             // compute wave?
  const int cw = w & 3;                 // strip index (compute or store)
  const int gx = blockIdx.x;
  const int z = gx & 31;                // gx%8 = z%8 -> XCD pin
  const int gq = gx >> 5;
  const int sB0 = gq << 7;              // 128 rows per block
  const int bb = z >> 4, hh = z & 15;
  const size_t zrow = (size_t)z * Sn;
  const size_t kRow = zrow * Dn;
  const int kw = cw << 9;               // strip's key base

  bf16x8 qHc[2][2], qLc[2][2], qHp[2][2], qLp[2][2];
  if (isC) load_q(qhH, qhL, zrow, sB0, l15, lg, qHc, qLc);

  float invqB[2] = {0.f, 0.f};
  f32x4 acc[2][4];

#pragma unroll 1
  for (int tau = 0; tau <= 4; ++tau) {
    const bool hasA = (tau < 4), hasB = (tau > 0);
    const int sBb = sB0 + ((tau - 1) << 5);
    float sum0 = 0.f, sum1 = 0.f;
    if (hasB && isC) {
#pragma unroll
      for (int qf = 0; qf < 2; ++qf)
#pragma unroll
        for (int g = 0; g < 4; ++g) acc[qf][g] = f32x4{0.f, 0.f, 0.f, 0.f};
    }

#pragma unroll 1
    for (int cc = 0; cc < 16; ++cc) {
      const int kbc = kw + (cc << 5);
      if (isC) {
#pragma unroll
        for (int t2 = 0; t2 < 2; ++t2) {
          const int kb = kbc + (t2 << 4);
          const bhalf* kp = khH + kRow + (size_t)(kb + l15) * Dn + lg * 8;
          const bhalf* kq = khL + kRow + (size_t)(kb + l15) * Dn + lg * 8;
          bf16x8 kH0 = *(const bf16x8*)kp, kH1 = *(const bf16x8*)(kp + 32);
          bf16x8 kL0 = *(const bf16x8*)kq, kL1 = *(const bf16x8*)(kq + 32);
          if (hasA) {
#pragma unroll
            for (int qf = 0; qf < 2; ++qf) {
              f32x4 cA = {}, cB = {};
              cA = MFMA16(kH0, qHc[qf][0], cA); cA = MFMA16(kH1, qHc[qf][1], cA);
              cB = MFMA16(kL0, qHc[qf][0], cB); cB = MFMA16(kL1, qHc[qf][1], cB);
              cA = MFMA16(kH0, qLc[qf][0], cA); cA = MFMA16(kH1, qLc[qf][1], cA);
              f32x4 c = cA + cB;
              float s = __expf(c[0] * 0.125f) + __expf(c[1] * 0.125f) +
                        __expf(c[2] * 0.125f) + __expf(c[3] * 0.125f);
              if (qf == 0) sum0 += s; else sum1 += s;
            }
          }
          if (hasB) {
#pragma unroll
            for (int qf = 0; qf < 2; ++qf) {
              f32x4 cA = {}, cB = {};
              cA = MFMA16(kH0, qHp[qf][0], cA); cA = MFMA16(kH1, qHp[qf][1], cA);
              cB = MFMA16(kL0, qHp[qf][0], cB); cB = MFMA16(kL1, qHp[qf][1], cB);
              cA = MFMA16(kH0, qLp[qf][0], cA); cA = MFMA16(kH1, qLp[qf][1], cA);
              f32x4 c = cA + cB;
              f32x4 p;
#pragma unroll
              for (int r = 0; r < 4; ++r)
                p[r] = __expf(c[r] * 0.125f) * invqB[qf];
              *(f32x4*)&ptd[cc & 1][cw][qf * 16 + l15][(t2 << 4) + (lg << 2)] = p;
            }
          }
        }
        if (hasB) {
          // PV on normalized p (own wave's buffer, no barrier needed)
#pragma unroll
          for (int qf = 0; qf < 2; ++qf) {
            f32x4 pa = *(const f32x4*)&ptd[cc & 1][cw][qf * 16 + l15][lg << 3];
            f32x4 pc = *(const f32x4*)&ptd[cc & 1][cw][qf * 16 + l15][(lg << 3) + 4];
            bf16x8 pbv;
#pragma unroll
            for (int e = 0; e < 4; ++e) {
              pbv[e] = (bhalf)pa[e];
              pbv[4 + e] = (bhalf)pc[e];
            }
#pragma unroll
            for (int g = 0; g < 4; ++g) {
              const bf16x8 va = *(const bf16x8*)(
                  vt + ((size_t)z * Dn + g * 16 + l15) * Sn + kbc + lg * 8);
              acc[qf][g] = MFMA16(va, pbv, acc[qf][g]);
            }
          }
        }
      } else if (hasB && cc > 0) {
        // store wave: drain chunk cc-1 of compute wave cw
        const int dc = cc - 1;
        const int kbd = kw + (dc << 5);
        const int srow = lane >> 3, scol = (lane & 7) << 2;
#pragma unroll
        for (int s = 0; s < 4; ++s) {
          const int row = (s << 3) + srow;
          f32x4 vv = *(const f32x4*)&ptd[dc & 1][cw][row][scol];
          __builtin_nontemporal_store(
              vv, (f32x4*)(attn + (zrow + sBb + row) * Sn + kbd + scol));
        }
      }
      __syncthreads();
    }

    // ---- phase boundary ----
    if (hasA && isC) {
      sum0 += __shfl_xor(sum0, 16); sum0 += __shfl_xor(sum0, 32);
      sum1 += __shfl_xor(sum1, 16); sum1 += __shfl_xor(sum1, 32);
      if (lane < 16) {
        lsum[cw][l15] = sum0;
        lsum[cw][16 + l15] = sum1;
      }
    }
    __syncthreads();
    if (hasA && tid < 32)
      linv[tid] =
          1.0f / (lsum[0][tid] + lsum[1][tid] + lsum[2][tid] + lsum[3][tid]);
    if (hasB) {
#pragma unroll
      for (int qf = 0; qf < 2; ++qf) {
        if (isC) {
#pragma unroll
          for (int g = 0; g < 4; ++g)
#pragma unroll
            for (int r = 0; r < 4; ++r)
              obuf[cw][l15][g * 16 + lg * 4 + r] = acc[qf][g][r];
        } else if (qf == 0) {
          // final drain: chunk 15 (visible via last cc barrier)
          const int kbd = kw + (15 << 5);
          const int srow = lane >> 3, scol = (lane & 7) << 2;
#pragma unroll
          for (int s = 0; s < 4; ++s) {
            const int row = (s << 3) + srow;
            f32x4 vv = *(const f32x4*)&ptd[1][cw][row][scol];
            __builtin_nontemporal_store(
                vv, (f32x4*)(attn + (zrow + sBb + row) * Sn + kbd + scol));
          }
        }
        __syncthreads();
        if (tid < 256) {
          const int qq = tid >> 4, d4 = (tid & 15) << 2;
          f32x4 rs = *(const f32x4*)&obuf[0][qq][d4];
          rs += *(const f32x4*)&obuf[1][qq][d4];
          rs += *(const f32x4*)&obuf[2][qq][d4];
          rs += *(const f32x4*)&obuf[3][qq][d4];
          const size_t off =
              ((size_t)bb * Sn + sBb + qf * 16 + qq) * Cn + hh * Dn + d4;
          bf16x4 hv, lv;
#pragma unroll
          for (int e = 0; e < 4; ++e) {
            bhalf h = (bhalf)rs[e];
            hv[e] = h;
            lv[e] = (bhalf)(rs[e] - (float)h);
          }
          *(bf16x4*)(ctxH + off) = hv;
          *(bf16x4*)(ctxL + off) = lv;
        }
        __syncthreads();
      }
    } else {
      __syncthreads();
    }
    if (hasA && isC) {
      invqB[0] = linv[l15];
      invqB[1] = linv[16 + l15];
#pragma unroll
      for (int qf = 0; qf < 2; ++qf)
#pragma unroll
        for (int sl = 0; sl < 2; ++sl) {
          qHp[qf][sl] = qHc[qf][sl];
          qLp[qf][sl] = qLc[qf][sl];
        }
      if (tau < 3)
        load_q(qhH, qhL, zrow, sB0 + ((tau + 1) << 5), l15, lg, qHc, qLc);
    }
  }
}

extern "C" void kernel_launch(void* const* d_in, const int* in_sizes, int n_in,
                              void* d_out, int out_size, void* d_ws, size_t ws_size,
                              hipStream_t stream) {
  const float* q = (const float*)d_in[0];
  const float* k = (const float*)d_in[1];
  const float* v = (const float*)d_in[2];
  const float* Wq = (const float*)d_in[3];
  const float* Wk = (const float*)d_in[4];
  const float* Wv = (const float*)d_in[5];
  const float* Wo = (const float*)d_in[6];

  float* out = (float*)d_out;                       // [B,S,C] 4M f32
  float* attn = out + (size_t)Mn * Cn;              // [B,H,S,S] 134M f32
  bhalf* vt = (bhalf*)d_out;                        // stash V^T (8MB) in out region

  bhalf* qhH = (bhalf*)d_ws;                        // 6 x 8MB = 48MB ws
  bhalf* qhL = qhH + (size_t)Mn * Cn;
  bhalf* khH = qhL + (size_t)Mn * Cn;
  bhalf* khL = khH + (size_t)Mn * Cn;
  bhalf* ctxH = khL + (size_t)Mn * Cn;
  bhalf* ctxL = ctxH + (size_t)Mn * Cn;

  dim3 gP(Cn / 64, Mn / 64);  // (16, 64)
  proj_mfma<1, false><<<gP, 256, 0, stream>>>(q, nullptr, Wq, nullptr, qhH, qhL);
  proj_mfma<1, false><<<gP, 256, 0, stream>>>(k, nullptr, Wk, nullptr, khH, khL);
  proj_mfma<2, false><<<gP, 256, 0, stream>>>(v, nullptr, Wv, nullptr, vt, nullptr);

  attn_fused<<<Zn * (Sn / 128), 512, 0, stream>>>(qhH, qhL, khH, khL, vt, attn,
                                                  ctxH, ctxL);

  proj_mfma<0, true><<<gP, 256, 0, stream>>>(ctxH, ctxL, Wo, out, nullptr, nullptr);
}

// Round 20
// 405.947 us; speedup vs baseline: 1.7942x; 1.7942x over previous
//
#include <hip/hip_runtime.h>
#include <cmath>

typedef __bf16 bhalf;
typedef __bf16 bf16x4 __attribute__((ext_vector_type(4)));
typedef __bf16 bf16x8 __attribute__((ext_vector_type(8)));
typedef float f32x4 __attribute__((ext_vector_type(4)));

#define MFMA16(a, b, c) __builtin_amdgcn_mfma_f32_16x16x32_bf16(a, b, c, 0, 0, 0)

namespace {
constexpr int Bn = 2, Sn = 2048, Cn = 1024, Hn = 16, Dn = 64;
constexpr int Zn = Bn * Hn;     // 32
constexpr int Mn = Bn * Sn;     // 4096
}

__device__ __forceinline__ void cvt_hilo8(const float4& v0, const float4& v1,
                                          bf16x8& hi, bf16x8& lo) {
  float f[8] = {v0.x, v0.y, v0.z, v0.w, v1.x, v1.y, v1.z, v1.w};
#pragma unroll
  for (int i = 0; i < 8; ++i) {
    bhalf h = (bhalf)f[i];
    hi[i] = h;
    lo[i] = (bhalf)(f[i] - (float)h);
  }
}

// Fused q/k/v projections: one 3072-block launch, grid.z selects input.
// z=0: q -> RoPE -> qhH/qhL; z=1: k -> RoPE -> khH/khL; z=2: v -> vt.
// K-loop identical to R12's proj_mfma (LDS-staged split-bf16 W).
__global__ __launch_bounds__(256) void proj_qkv(
    const float* __restrict__ qin, const float* __restrict__ kin,
    const float* __restrict__ vin, const float* __restrict__ Wq,
    const float* __restrict__ Wk, const float* __restrict__ Wv,
    bhalf* __restrict__ qhH, bhalf* __restrict__ qhL,
    bhalf* __restrict__ khH, bhalf* __restrict__ khL,
    bhalf* __restrict__ vt) {
  __shared__ bhalf BsH[64][40];
  __shared__ bhalf BsL[64][40];
  const int tid = threadIdx.x;
  const int lane = tid & 63, w = tid >> 6;
  const int l15 = lane & 15, lg = lane >> 4;
  const int nB = blockIdx.x << 6, mB = blockIdx.y << 6;
  const int which = blockIdx.z;
  const float* X = (which == 0) ? qin : (which == 1) ? kin : vin;
  const float* W = (which == 0) ? Wq : (which == 1) ? Wk : Wv;
  const int row = mB + w * 16 + l15;
  f32x4 acc[4] = {};

  const int sr = tid >> 2, sc = (tid & 3) << 3;
  for (int k0 = 0; k0 < Cn; k0 += 32) {
    {
      const float* wp = W + (size_t)(nB + sr) * Cn + k0 + sc;
      float4 w0 = *(const float4*)wp;
      float4 w1 = *(const float4*)(wp + 4);
      bf16x8 h, l;
      cvt_hilo8(w0, w1, h, l);
      *(bf16x8*)&BsH[sr][sc] = h;
      *(bf16x8*)&BsL[sr][sc] = l;
    }
    __syncthreads();
    float4 a0 = *(const float4*)(X + (size_t)row * Cn + k0 + lg * 8);
    float4 a1 = *(const float4*)(X + (size_t)row * Cn + k0 + lg * 8 + 4);
    bf16x8 aH, aL;
    cvt_hilo8(a0, a1, aH, aL);
#pragma unroll
    for (int j = 0; j < 4; ++j) {
      bf16x8 bH = *(const bf16x8*)&BsH[16 * j + l15][lg * 8];
      bf16x8 bL = *(const bf16x8*)&BsL[16 * j + l15][lg * 8];
      acc[j] = MFMA16(aH, bH, acc[j]);
      acc[j] = MFMA16(aH, bL, acc[j]);
      acc[j] = MFMA16(aL, bH, acc[j]);
    }
    __syncthreads();
  }

  const int mRow = mB + w * 16 + lg * 4;
  const int hh = nB >> 6;
  if (which < 2) {
    bhalf* dst_hi = (which == 0) ? qhH : khH;
    bhalf* dst_lo = (which == 0) ? qhL : khL;
#pragma unroll
    for (int jj = 0; jj < 2; ++jj) {
      const int d1 = 16 * jj + l15;
      const float invf = 1.0f / powf(10000.0f, (float)d1 * (1.0f / 32.0f));
#pragma unroll
      for (int r = 0; r < 4; ++r) {
        const int m = mRow + r;
        const int b = m >> 11, s = m & (Sn - 1);
        float sn, cs;
        sincosf((float)s * invf, &sn, &cs);
        const float y1 = acc[jj][r], y2 = acc[jj + 2][r];
        const float o1 = y1 * cs - y2 * sn;
        const float o2 = y2 * cs + y1 * sn;
        const size_t base = (((size_t)(b * Hn + hh)) * Sn + s) * Dn;
        bhalf h1 = (bhalf)o1, h2 = (bhalf)o2;
        dst_hi[base + d1] = h1;
        dst_lo[base + d1] = (bhalf)(o1 - (float)h1);
        dst_hi[base + d1 + 32] = h2;
        dst_lo[base + d1 + 32] = (bhalf)(o2 - (float)h2);
      }
    }
  } else {
#pragma unroll
    for (int j = 0; j < 4; ++j) {
      const int d = 16 * j + l15;
#pragma unroll
      for (int r = 0; r < 4; ++r) {
        const int m = mRow + r;
        const int b = m >> 11, s = m & (Sn - 1);
        vt[(((size_t)(b * Hn + hh)) * Dn + d) * Sn + s] = (bhalf)acc[j][r];
      }
    }
  }
}

// Final projection (ctx hi/lo bf16) x Wo^T -> out f32. (R12's MODE 0)
__global__ __launch_bounds__(256) void proj_out(
    const bhalf* __restrict__ AH, const bhalf* __restrict__ AL,
    const float* __restrict__ W, float* __restrict__ out_f32) {
  __shared__ bhalf BsH[64][40];
  __shared__ bhalf BsL[64][40];
  const int tid = threadIdx.x;
  const int lane = tid & 63, w = tid >> 6;
  const int l15 = lane & 15, lg = lane >> 4;
  const int nB = blockIdx.x << 6, mB = blockIdx.y << 6;
  const int row = mB + w * 16 + l15;
  f32x4 acc[4] = {};

  const int sr = tid >> 2, sc = (tid & 3) << 3;
  for (int k0 = 0; k0 < Cn; k0 += 32) {
    {
      const float* wp = W + (size_t)(nB + sr) * Cn + k0 + sc;
      float4 w0 = *(const float4*)wp;
      float4 w1 = *(const float4*)(wp + 4);
      bf16x8 h, l;
      cvt_hilo8(w0, w1, h, l);
      *(bf16x8*)&BsH[sr][sc] = h;
      *(bf16x8*)&BsL[sr][sc] = l;
    }
    __syncthreads();
    bf16x8 aH = *(const bf16x8*)(AH + (size_t)row * Cn + k0 + lg * 8);
    bf16x8 aL = *(const bf16x8*)(AL + (size_t)row * Cn + k0 + lg * 8);
#pragma unroll
    for (int j = 0; j < 4; ++j) {
      bf16x8 bH = *(const bf16x8*)&BsH[16 * j + l15][lg * 8];
      bf16x8 bL = *(const bf16x8*)&BsL[16 * j + l15][lg * 8];
      acc[j] = MFMA16(aH, bH, acc[j]);
      acc[j] = MFMA16(aH, bL, acc[j]);
      acc[j] = MFMA16(aL, bH, acc[j]);
    }
    __syncthreads();
  }

  const int mRow = mB + w * 16 + lg * 4;
#pragma unroll
  for (int j = 0; j < 4; ++j) {
    const int n = nB + 16 * j + l15;
#pragma unroll
    for (int r = 0; r < 4; ++r)
      out_f32[(size_t)(mRow + r) * Cn + n] = acc[j][r];
  }
}

__device__ __forceinline__ void load_q(const bhalf* __restrict__ qhH,
                                       const bhalf* __restrict__ qhL,
                                       size_t zrow, int sBt, int l15, int lg,
                                       bf16x8 (&qH)[2][2], bf16x8 (&qL)[2][2]) {
#pragma unroll
  for (int qf = 0; qf < 2; ++qf)
#pragma unroll
    for (int sl = 0; sl < 2; ++sl) {
      const size_t off = (zrow + sBt + qf * 16 + l15) * Dn + sl * 32 + lg * 8;
      qH[qf][sl] = *(const bf16x8*)(qhH + off);
      qL[qf][sl] = *(const bf16x8*)(qhL + off);
    }
}

// Fused attention v9 (R12, byte-for-byte — 433.9us best).
__global__ __launch_bounds__(256) void attn_fused(
    const bhalf* __restrict__ qhH, const bhalf* __restrict__ qhL,
    const bhalf* __restrict__ khH, const bhalf* __restrict__ khL,
    const bhalf* __restrict__ vt, float* __restrict__ attn,
    bhalf* __restrict__ ctxH, bhalf* __restrict__ ctxL) {
  __shared__ float pt[4][32][36];
  __shared__ float lsum[4][32];
  __shared__ float linv[32];

  const int tid = threadIdx.x, lane = tid & 63, w = tid >> 6;
  const int l15 = lane & 15, lg = lane >> 4;
  const int gx = blockIdx.x;
  const int z = gx & 31;
  const int gq = gx >> 5;
  const int sB0 = gq << 7;
  const int bb = z >> 4, hh = z & 15;
  const size_t zrow = (size_t)z * Sn;
  const size_t kRow = zrow * Dn;
  const int kw = w << 9;

  bf16x8 qHc[2][2], qLc[2][2], qHp[2][2], qLp[2][2];
  load_q(qhH, qhL, zrow, sB0, l15, lg, qHc, qLc);

  float invqB[2] = {0.f, 0.f};
  f32x4 acc[2][4];

#pragma unroll 1
  for (int tau = 0; tau <= 4; ++tau) {
    const bool hasA = (tau < 4), hasB = (tau > 0);
    const int sBb = sB0 + ((tau - 1) << 5);
    float sum0 = 0.f, sum1 = 0.f;
    if (hasB) {
#pragma unroll
      for (int qf = 0; qf < 2; ++qf)
#pragma unroll
        for (int g = 0; g < 4; ++g) acc[qf][g] = f32x4{0.f, 0.f, 0.f, 0.f};
    }

#pragma unroll 1
    for (int cc = 0; cc < 16; ++cc) {
      const int kbc = kw + (cc << 5);
#pragma unroll
      for (int t2 = 0; t2 < 2; ++t2) {
        const int kb = kbc + (t2 << 4);
        const bhalf* kp = khH + kRow + (size_t)(kb + l15) * Dn + lg * 8;
        const bhalf* kq = khL + kRow + (size_t)(kb + l15) * Dn + lg * 8;
        bf16x8 kH0 = *(const bf16x8*)kp, kH1 = *(const bf16x8*)(kp + 32);
        bf16x8 kL0 = *(const bf16x8*)kq, kL1 = *(const bf16x8*)(kq + 32);
        if (hasA) {
#pragma unroll
          for (int qf = 0; qf < 2; ++qf) {
            f32x4 cA = {}, cB = {};
            cA = MFMA16(kH0, qHc[qf][0], cA); cA = MFMA16(kH1, qHc[qf][1], cA);
            cB = MFMA16(kL0, qHc[qf][0], cB); cB = MFMA16(kL1, qHc[qf][1], cB);
            cA = MFMA16(kH0, qLc[qf][0], cA); cA = MFMA16(kH1, qLc[qf][1], cA);
            f32x4 c = cA + cB;
            float s = __expf(c[0] * 0.125f) + __expf(c[1] * 0.125f) +
                      __expf(c[2] * 0.125f) + __expf(c[3] * 0.125f);
            if (qf == 0) sum0 += s; else sum1 += s;
          }
        }
        if (hasB) {
#pragma unroll
          for (int qf = 0; qf < 2; ++qf) {
            f32x4 cA = {}, cB = {};
            cA = MFMA16(kH0, qHp[qf][0], cA); cA = MFMA16(kH1, qHp[qf][1], cA);
            cB = MFMA16(kL0, qHp[qf][0], cB); cB = MFMA16(kL1, qHp[qf][1], cB);
            cA = MFMA16(kH0, qLp[qf][0], cA); cA = MFMA16(kH1, qLp[qf][1], cA);
            f32x4 c = cA + cB;
            f32x4 p;
#pragma unroll
            for (int r = 0; r < 4; ++r)
              p[r] = __expf(c[r] * 0.125f) * invqB[qf];
            *(f32x4*)&pt[w][qf * 16 + l15][(t2 << 4) + (lg << 2)] = p;
          }
        }
      }
      if (hasB) {
        const int srow = lane >> 3, scol = (lane & 7) << 2;
#pragma unroll
        for (int s = 0; s < 4; ++s) {
          const int row = (s << 3) + srow;
          f32x4 vv = *(const f32x4*)&pt[w][row][scol];
          __builtin_nontemporal_store(
              vv, (f32x4*)(attn + (zrow + sBb + row) * Sn + kbc + scol));
        }
#pragma unroll
        for (int qf = 0; qf < 2; ++qf) {
          f32x4 pa = *(const f32x4*)&pt[w][qf * 16 + l15][lg << 3];
          f32x4 pc = *(const f32x4*)&pt[w][qf * 16 + l15][(lg << 3) + 4];
          bf16x8 pbv;
#pragma unroll
          for (int e = 0; e < 4; ++e) {
            pbv[e] = (bhalf)pa[e];
            pbv[4 + e] = (bhalf)pc[e];
          }
#pragma unroll
          for (int g = 0; g < 4; ++g) {
            const bf16x8 va = *(const bf16x8*)(
                vt + ((size_t)z * Dn + g * 16 + l15) * Sn + kbc + lg * 8);
            acc[qf][g] = MFMA16(va, pbv, acc[qf][g]);
          }
        }
      }
    }

    if (hasA) {
      sum0 += __shfl_xor(sum0, 16); sum0 += __shfl_xor(sum0, 32);
      sum1 += __shfl_xor(sum1, 16); sum1 += __shfl_xor(sum1, 32);
      if (lane < 16) {
        lsum[w][l15] = sum0;
        lsum[w][16 + l15] = sum1;
      }
    }
    __syncthreads();
    if (hasA && tid < 32)
      linv[tid] =
          1.0f / (lsum[0][tid] + lsum[1][tid] + lsum[2][tid] + lsum[3][tid]);
    if (hasB) {
      float* fb = (float*)&pt[w][0][0];
      float* fb0 = (float*)&pt[0][0][0];
      float* fb1 = (float*)&pt[1][0][0];
      float* fb2 = (float*)&pt[2][0][0];
      float* fb3 = (float*)&pt[3][0][0];
#pragma unroll
      for (int qf = 0; qf < 2; ++qf) {
#pragma unroll
        for (int g = 0; g < 4; ++g)
#pragma unroll
          for (int r = 0; r < 4; ++r)
            fb[l15 * 72 + g * 16 + lg * 4 + r] = acc[qf][g][r];
        __syncthreads();
        {
          const int qq = tid >> 4, d4 = (tid & 15) << 2;
          f32x4 rs = *(const f32x4*)&fb0[qq * 72 + d4];
          rs += *(const f32x4*)&fb1[qq * 72 + d4];
          rs += *(const f32x4*)&fb2[qq * 72 + d4];
          rs += *(const f32x4*)&fb3[qq * 72 + d4];
          const size_t off =
              ((size_t)bb * Sn + sBb + qf * 16 + qq) * Cn + hh * Dn + d4;
          bf16x4 hv, lv;
#pragma unroll
          for (int e = 0; e < 4; ++e) {
            bhalf h = (bhalf)rs[e];
            hv[e] = h;
            lv[e] = (bhalf)(rs[e] - (float)h);
          }
          *(bf16x4*)(ctxH + off) = hv;
          *(bf16x4*)(ctxL + off) = lv;
        }
        __syncthreads();
      }
    } else {
      __syncthreads();
    }
    if (hasA) {
      invqB[0] = linv[l15];
      invqB[1] = linv[16 + l15];
#pragma unroll
      for (int qf = 0; qf < 2; ++qf)
#pragma unroll
        for (int sl = 0; sl < 2; ++sl) {
          qHp[qf][sl] = qHc[qf][sl];
          qLp[qf][sl] = qLc[qf][sl];
        }
      if (tau < 3)
        load_q(qhH, qhL, zrow, sB0 + ((tau + 1) << 5), l15, lg, qHc, qLc);
    }
  }
}

extern "C" void kernel_launch(void* const* d_in, const int* in_sizes, int n_in,
                              void* d_out, int out_size, void* d_ws, size_t ws_size,
                              hipStream_t stream) {
  const float* q = (const float*)d_in[0];
  const float* k = (const float*)d_in[1];
  const float* v = (const float*)d_in[2];
  const float* Wq = (const float*)d_in[3];
  const float* Wk = (const float*)d_in[4];
  const float* Wv = (const float*)d_in[5];
  const float* Wo = (const float*)d_in[6];

  float* out = (float*)d_out;                       // [B,S,C] 4M f32
  float* attn = out + (size_t)Mn * Cn;              // [B,H,S,S] 134M f32
  bhalf* vt = (bhalf*)d_out;                        // stash V^T (8MB) in out region

  bhalf* qhH = (bhalf*)d_ws;                        // 6 x 8MB = 48MB ws
  bhalf* qhL = qhH + (size_t)Mn * Cn;
  bhalf* khH = qhL + (size_t)Mn * Cn;
  bhalf* khL = khH + (size_t)Mn * Cn;
  bhalf* ctxH = khL + (size_t)Mn * Cn;
  bhalf* ctxL = ctxH + (size_t)Mn * Cn;

  dim3 gP3(Cn / 64, Mn / 64, 3);  // fused q/k/v projections, one launch
  proj_qkv<<<gP3, 256, 0, stream>>>(q, k, v, Wq, Wk, Wv, qhH, qhL, khH, khL, vt);

  attn_fused<<<Zn * (Sn / 128), 256, 0, stream>>>(qhH, qhL, khH, khL, vt, attn,
                                                  ctxH, ctxL);

  dim3 gP(Cn / 64, Mn / 64);
  proj_out<<<gP, 256, 0, stream>>>(ctxH, ctxL, Wo, out);
}